// Round 1
// baseline (4376.612 us; speedup 1.0000x reference)
//
#include <hip/hip_runtime.h>
#include <math.h>

#define NTOK 32768
#define DIM 512
#define KC 8192

#define BN 64
#define BK 64
#define DC 32
#define PAD 68   // LDS row stride (floats): keeps b128 reads 16B-aligned, breaks worst conflicts

// ---------------- Kernel A: c2[k] = sum_d W[k][d]^2 ----------------
__global__ __launch_bounds__(256) void c2_kernel(const float* __restrict__ W,
                                                 float* __restrict__ c2) {
    int wid = threadIdx.x >> 6;
    int lane = threadIdx.x & 63;
    int row = blockIdx.x * 4 + wid;
    const float* wr = W + (size_t)row * DIM;
    float s = 0.f;
#pragma unroll
    for (int q = 0; q < 2; ++q) {
        float4 v = *(const float4*)(wr + q * 256 + lane * 4);
        s += v.x * v.x + v.y * v.y + v.z * v.z + v.w * v.w;
    }
#pragma unroll
    for (int off = 32; off > 0; off >>= 1) s += __shfl_down(s, off);
    if (lane == 0) c2[row] = s;
}

// ---------------- Kernel B: fused GEMM + argmin ----------------
// score(n,k) = c2[k] - 2 * dot(x[n], W[k]); argmin_k matches full-dist argmin
// (||x||^2 is constant per row).
__global__ __launch_bounds__(256) void argmin_kernel(const float* __restrict__ x,
                                                     const float* __restrict__ W,
                                                     const float* __restrict__ c2,
                                                     float* __restrict__ idsf) {
    __shared__ float xs[DC][PAD];
    __shared__ float wt[DC][PAD];
    __shared__ float c2s[BK];
    __shared__ float redv[16][BN];
    __shared__ int   redi[16][BN];

    const int tid = threadIdx.x;
    const int n0 = blockIdx.x * BN;
    const int i = tid & 15;   // token group: tokens i*4 .. i*4+3
    const int j = tid >> 4;   // code group:  codes  j*4 .. j*4+3

    float bestv[4];
    int   besti[4];
#pragma unroll
    for (int t = 0; t < 4; ++t) { bestv[t] = 3.4e38f; besti[t] = 0; }

    for (int k0 = 0; k0 < KC; k0 += BK) {
        __syncthreads();                 // protect c2s reads from previous epilogue
        if (tid < BK) c2s[tid] = c2[k0 + tid];

        float acc[4][4];
#pragma unroll
        for (int a = 0; a < 4; ++a)
#pragma unroll
            for (int b = 0; b < 4; ++b) acc[a][b] = 0.f;

        for (int d0 = 0; d0 < DIM; d0 += DC) {
            __syncthreads();             // protect previous chunk's LDS reads
            // stage x-chunk and W-chunk transposed: [d][token/code]
#pragma unroll
            for (int r = 0; r < 2; ++r) {
                int f = tid + r * 256;
                int tok = f >> 3;        // 0..63
                int dq = f & 7;          // float4 index within 32-d chunk
                float4 xv = *(const float4*)(x + (size_t)(n0 + tok) * DIM + d0 + dq * 4);
                float4 wv = *(const float4*)(W + (size_t)(k0 + tok) * DIM + d0 + dq * 4);
                xs[dq * 4 + 0][tok] = xv.x; xs[dq * 4 + 1][tok] = xv.y;
                xs[dq * 4 + 2][tok] = xv.z; xs[dq * 4 + 3][tok] = xv.w;
                wt[dq * 4 + 0][tok] = wv.x; wt[dq * 4 + 1][tok] = wv.y;
                wt[dq * 4 + 2][tok] = wv.z; wt[dq * 4 + 3][tok] = wv.w;
            }
            __syncthreads();
#pragma unroll
            for (int d = 0; d < DC; ++d) {
                float4 xv = *(const float4*)(&xs[d][i * 4]);
                float4 wv = *(const float4*)(&wt[d][j * 4]);
                acc[0][0] = fmaf(xv.x, wv.x, acc[0][0]);
                acc[0][1] = fmaf(xv.x, wv.y, acc[0][1]);
                acc[0][2] = fmaf(xv.x, wv.z, acc[0][2]);
                acc[0][3] = fmaf(xv.x, wv.w, acc[0][3]);
                acc[1][0] = fmaf(xv.y, wv.x, acc[1][0]);
                acc[1][1] = fmaf(xv.y, wv.y, acc[1][1]);
                acc[1][2] = fmaf(xv.y, wv.z, acc[1][2]);
                acc[1][3] = fmaf(xv.y, wv.w, acc[1][3]);
                acc[2][0] = fmaf(xv.z, wv.x, acc[2][0]);
                acc[2][1] = fmaf(xv.z, wv.y, acc[2][1]);
                acc[2][2] = fmaf(xv.z, wv.z, acc[2][2]);
                acc[2][3] = fmaf(xv.z, wv.w, acc[2][3]);
                acc[3][0] = fmaf(xv.w, wv.x, acc[3][0]);
                acc[3][1] = fmaf(xv.w, wv.y, acc[3][1]);
                acc[3][2] = fmaf(xv.w, wv.z, acc[3][2]);
                acc[3][3] = fmaf(xv.w, wv.w, acc[3][3]);
            }
        }
        // epilogue: scores + running argmin (ascending k scan => first-occurrence ties)
#pragma unroll
        for (int ti = 0; ti < 4; ++ti) {
#pragma unroll
            for (int cj = 0; cj < 4; ++cj) {
                float s = c2s[j * 4 + cj] - 2.f * acc[ti][cj];
                int kk = k0 + j * 4 + cj;
                if (s < bestv[ti]) { bestv[ti] = s; besti[ti] = kk; }
            }
        }
    }

    // cross-thread reduce over the 16 j-groups per token
#pragma unroll
    for (int ti = 0; ti < 4; ++ti) {
        redv[j][i * 4 + ti] = bestv[ti];
        redi[j][i * 4 + ti] = besti[ti];
    }
    __syncthreads();
    if (tid < BN) {
        float bv = redv[0][tid];
        int   bi = redi[0][tid];
#pragma unroll
        for (int jj = 1; jj < 16; ++jj) {
            float v = redv[jj][tid];
            int  ii = redi[jj][tid];
            if (v < bv || (v == bv && ii < bi)) { bv = v; bi = ii; }
        }
        idsf[n0 + tid] = (float)bi;
    }
}

// ---------------- Kernel C: gather emb, write emb_out, partial loss ----------------
__global__ __launch_bounds__(256) void gather_kernel(const float* __restrict__ x,
                                                     const float* __restrict__ W,
                                                     const float* __restrict__ idsf,
                                                     float* __restrict__ emb_out,
                                                     float* __restrict__ partials) {
    int wid = threadIdx.x >> 6;
    int lane = threadIdx.x & 63;
    int tok = blockIdx.x * 4 + wid;
    int id = (int)idsf[tok];
    const float* wr = W + (size_t)id * DIM;
    const float* xr = x + (size_t)tok * DIM;
    float* orow = emb_out + (size_t)tok * DIM;
    float s = 0.f;
#pragma unroll
    for (int q = 0; q < 2; ++q) {
        int d = q * 256 + lane * 4;
        float4 wv = *(const float4*)(wr + d);
        float4 xv = *(const float4*)(xr + d);
        float4 e;
        e.x = xv.x + (wv.x - xv.x);
        e.y = xv.y + (wv.y - xv.y);
        e.z = xv.z + (wv.z - xv.z);
        e.w = xv.w + (wv.w - xv.w);
        *(float4*)(orow + d) = e;
        float dx = xv.x - wv.x;
        float dy = xv.y - wv.y;
        float dz = xv.z - wv.z;
        float dw = xv.w - wv.w;
        s += dx * dx + dy * dy + dz * dz + dw * dw;
    }
#pragma unroll
    for (int off = 32; off > 0; off >>= 1) s += __shfl_down(s, off);
    __shared__ float bsum[4];
    if (lane == 0) bsum[wid] = s;
    __syncthreads();
    if (threadIdx.x == 0)
        partials[blockIdx.x] = bsum[0] + bsum[1] + bsum[2] + bsum[3];
}

// ---------------- Kernel D: final loss ----------------
__global__ __launch_bounds__(256) void loss_kernel(const float* __restrict__ partials,
                                                   float* __restrict__ lossp) {
    __shared__ float red[256];
    float s = 0.f;
    for (int idx = threadIdx.x; idx < NTOK / 4; idx += 256) s += partials[idx];
    red[threadIdx.x] = s;
    __syncthreads();
    for (int off = 128; off > 0; off >>= 1) {
        if (threadIdx.x < off) red[threadIdx.x] += red[threadIdx.x + off];
        __syncthreads();
    }
    if (threadIdx.x == 0) lossp[0] = 1.25f * red[0] / (float)NTOK;
}

extern "C" void kernel_launch(void* const* d_in, const int* in_sizes, int n_in,
                              void* d_out, int out_size, void* d_ws, size_t ws_size,
                              hipStream_t stream) {
    const float* x = (const float*)d_in[0];
    // d_in[1] = temperature (unused by the reference computation)
    const float* W = (const float*)d_in[2];

    float* out = (float*)d_out;
    float* emb_out = out;                              // [32768*512]
    float* idsf = out + (size_t)NTOK * DIM;            // [32768] ids as float
    float* lossp = idsf + NTOK;                        // [1]

    float* ws = (float*)d_ws;
    float* c2 = ws;                                    // [8192]
    float* partials = ws + KC;                         // [8192]

    c2_kernel<<<KC / 4, 256, 0, stream>>>(W, c2);
    argmin_kernel<<<NTOK / BN, 256, 0, stream>>>(x, W, c2, idsf);
    gather_kernel<<<NTOK / 4, 256, 0, stream>>>(x, W, idsf, emb_out, partials);
    loss_kernel<<<1, 256, 0, stream>>>(partials, lossp);
}

// Round 2
// 1524.759 us; speedup vs baseline: 2.8704x; 2.8704x over previous
//
#include <hip/hip_runtime.h>
#include <math.h>

#define NTOK 32768
#define DIM 512
#define KC 8192
#define TSTEPS 16          // 512 / 32 d-steps

typedef unsigned short u16;
typedef _Float16 half8 __attribute__((ext_vector_type(8)));
typedef float f32x4 __attribute__((ext_vector_type(4)));

// ---- async global->LDS, 16B per lane (dest linear: base + lane*16) ----
__device__ __forceinline__ void gload16(const void* g, void* l) {
    __builtin_amdgcn_global_load_lds(
        (const __attribute__((address_space(1))) unsigned int*)(void*)g,
        (__attribute__((address_space(3))) unsigned int*)l, 16, 0, 0);
}

// ================= shared small kernels =================
__global__ __launch_bounds__(256) void c2_kernel(const float* __restrict__ W,
                                                 float* __restrict__ c2) {
    int wid = threadIdx.x >> 6;
    int lane = threadIdx.x & 63;
    int row = blockIdx.x * 4 + wid;
    const float* wr = W + (size_t)row * DIM;
    float s = 0.f;
#pragma unroll
    for (int q = 0; q < 2; ++q) {
        float4 v = *(const float4*)(wr + q * 256 + lane * 4);
        s += v.x * v.x + v.y * v.y + v.z * v.z + v.w * v.w;
    }
#pragma unroll
    for (int off = 32; off > 0; off >>= 1) s += __shfl_down(s, off);
    if (lane == 0) c2[row] = s;
}

__global__ __launch_bounds__(256) void loss_kernel(const float* __restrict__ partials,
                                                   float* __restrict__ lossp) {
    __shared__ float red[256];
    float s = 0.f;
    for (int idx = threadIdx.x; idx < NTOK / 4; idx += 256) s += partials[idx];
    red[threadIdx.x] = s;
    __syncthreads();
    for (int off = 128; off > 0; off >>= 1) {
        if (threadIdx.x < off) red[threadIdx.x] += red[threadIdx.x + off];
        __syncthreads();
    }
    if (threadIdx.x == 0) lossp[0] = 1.25f * red[0] / (float)NTOK;
}

// ================= fp16-split MFMA path =================
// Scratch layout per source matrix (rows x 512 fp32):
//   tiles of 128 rows; per tile, 16 d-steps; per step, 128 rows x 128B.
//   A row's 128B = 8 chunks of 16B (8 fp16): chunks 0-3 = hi-plane d-chunks,
//   4-7 = lo-plane; chunk c stored at slot c ^ (row&7)  (bank-conflict-free
//   ds_read_b128 after linear global_load_lds staging).
__global__ __launch_bounds__(256) void split_kernel(const float* __restrict__ src,
                                                    u16* __restrict__ dst) {
    int t = blockIdx.x * 256 + threadIdx.x;
    int row = t >> 6;
    int dc = t & 63;                       // 8-elem d-chunk index
    const float* p = src + (size_t)row * DIM + dc * 8;
    float4 va = *(const float4*)p;
    float4 vb = *(const float4*)(p + 4);
    float f[8] = {va.x, va.y, va.z, va.w, vb.x, vb.y, vb.z, vb.w};
    unsigned hi[4], lo[4];
#pragma unroll
    for (int j = 0; j < 4; ++j) {
        _Float16 h0 = (_Float16)f[2 * j];
        float r0 = f[2 * j] - (float)h0;
        _Float16 g0 = (_Float16)r0;
        _Float16 h1 = (_Float16)f[2 * j + 1];
        float r1 = f[2 * j + 1] - (float)h1;
        _Float16 g1 = (_Float16)r1;
        hi[j] = (unsigned)__builtin_bit_cast(u16, h0) |
                ((unsigned)__builtin_bit_cast(u16, h1) << 16);
        lo[j] = (unsigned)__builtin_bit_cast(u16, g0) |
                ((unsigned)__builtin_bit_cast(u16, g1) << 16);
    }
    int tile = row >> 7, R = row & 127, step = dc >> 2, kblk = dc & 3;
    int sw = R & 7;
    u16* base = dst + ((size_t)(tile * TSTEPS + step) * 128 + R) * 64;
    uint4 H = {hi[0], hi[1], hi[2], hi[3]};
    uint4 L = {lo[0], lo[1], lo[2], lo[3]};
    *(uint4*)(base + (size_t)((kblk ^ sw) * 8)) = H;
    *(uint4*)(base + (size_t)(((kblk + 4) ^ sw) * 8)) = L;
}

__global__ void init_keys_kernel(unsigned long long* keys) {
    keys[blockIdx.x * 256 + threadIdx.x] = ~0ull;
}

__global__ __launch_bounds__(256, 2) void argmin_mfma_kernel(
    const u16* __restrict__ xscr, const u16* __restrict__ wscr,
    const float* __restrict__ c2, unsigned long long* __restrict__ keys) {
    __shared__ __align__(16) u16 Abuf[2][128 * 64];
    __shared__ __align__(16) u16 Bbuf[2][128 * 64];

    // XCD-aware swizzle (16384 % 8 == 0 -> simple form bijective)
    int cpx = gridDim.x >> 3;
    int bid = blockIdx.x;
    int wg = (bid & 7) * cpx + (bid >> 3);
    int tcol = wg & 63;    // code tile (128 codes)
    int trow = wg >> 6;    // token tile (128 tokens)

    const int tid = threadIdx.x;
    const int lane = tid & 63;
    const int w = tid >> 6;
    const int wr = w >> 1, wc = w & 1;   // wave's 64x64 quadrant

    const char* gA = (const char*)(xscr + (size_t)trow * (TSTEPS * 128 * 64));
    const char* gB = (const char*)(wscr + (size_t)tcol * (TSTEPS * 128 * 64));
    const size_t stepBytes = 128 * 128;

    float c2v[4];
    const int colbase = tcol * 128 + wc * 64 + (lane & 15);
#pragma unroll
    for (int n = 0; n < 4; ++n) c2v[n] = c2[colbase + n * 16];

    f32x4 acc[4][4];
#pragma unroll
    for (int m = 0; m < 4; ++m)
#pragma unroll
        for (int n = 0; n < 4; ++n) acc[m][n] = f32x4{0.f, 0.f, 0.f, 0.f};

    const int rA = wr * 64 + (lane & 15);
    const int rB = wc * 64 + (lane & 15);
    const int c1 = ((lane >> 4) ^ (lane & 7)) * 8;         // hi-plane chunk slot
    const int c2o = (((lane >> 4) + 4) ^ (lane & 7)) * 8;  // lo-plane chunk slot

    // prologue: stage step 0 into buf 0 (8 x 1KB wave-loads per wave)
#pragma unroll
    for (int l = 0; l < 4; ++l) {
        int i = w * 4 + l;
        gload16(gA + i * 1024 + lane * 16, &Abuf[0][i * 512]);
        gload16(gB + i * 1024 + lane * 16, &Bbuf[0][i * 512]);
    }
    __syncthreads();

    int cur = 0;
    for (int s = 0; s < TSTEPS; ++s) {
        if (s + 1 < TSTEPS) {
            const char* gAs = gA + (size_t)(s + 1) * stepBytes;
            const char* gBs = gB + (size_t)(s + 1) * stepBytes;
#pragma unroll
            for (int l = 0; l < 4; ++l) {
                int i = w * 4 + l;
                gload16(gAs + i * 1024 + lane * 16, &Abuf[cur ^ 1][i * 512]);
                gload16(gBs + i * 1024 + lane * 16, &Bbuf[cur ^ 1][i * 512]);
            }
        }
        const u16* Ab = Abuf[cur];
        const u16* Bb = Bbuf[cur];
        half8 a1[4], a2[4], b1[4], b2[4];
#pragma unroll
        for (int m = 0; m < 4; ++m) {
            a1[m] = *(const half8*)(Ab + (rA + m * 16) * 64 + c1);
            a2[m] = *(const half8*)(Ab + (rA + m * 16) * 64 + c2o);
        }
#pragma unroll
        for (int n = 0; n < 4; ++n) {
            b1[n] = *(const half8*)(Bb + (rB + n * 16) * 64 + c1);
            b2[n] = *(const half8*)(Bb + (rB + n * 16) * 64 + c2o);
        }
#pragma unroll
        for (int m = 0; m < 4; ++m)
#pragma unroll
            for (int n = 0; n < 4; ++n) {
                acc[m][n] = __builtin_amdgcn_mfma_f32_16x16x32_f16(a1[m], b1[n], acc[m][n], 0, 0, 0);
                acc[m][n] = __builtin_amdgcn_mfma_f32_16x16x32_f16(a2[m], b1[n], acc[m][n], 0, 0, 0);
                acc[m][n] = __builtin_amdgcn_mfma_f32_16x16x32_f16(a1[m], b2[n], acc[m][n], 0, 0, 0);
            }
        __syncthreads();
        cur ^= 1;
    }

    // epilogue: score = c2[k] - 2*dot; per-row argmin over 128-code tile,
    // then one deterministic u64 atomicMin per row (val-monotonic | idx).
    const int rowg0 = trow * 128 + wr * 64 + (lane >> 4) * 4;
#pragma unroll
    for (int m = 0; m < 4; ++m) {
#pragma unroll
        for (int r = 0; r < 4; ++r) {
            float bv = 3.4e38f;
            int bi = 0;
#pragma unroll
            for (int n = 0; n < 4; ++n) {
                float sc = c2v[n] - 2.0f * acc[m][n][r];
                int idx = colbase + n * 16;
                if (sc < bv) { bv = sc; bi = idx; }
            }
#pragma unroll
            for (int off = 1; off < 16; off <<= 1) {
                float ov = __shfl_xor(bv, off);
                int oi = __shfl_xor(bi, off);
                if (ov < bv || (ov == bv && oi < bi)) { bv = ov; bi = oi; }
            }
            if ((lane & 15) == 0) {
                unsigned u = __float_as_uint(bv);
                u = (u & 0x80000000u) ? ~u : (u | 0x80000000u);
                unsigned long long key = ((unsigned long long)u << 32) | (unsigned)bi;
                atomicMin(&keys[rowg0 + m * 16 + r], key);
            }
        }
    }
}

__global__ __launch_bounds__(256) void gather_keys_kernel(
    const float* __restrict__ x, const float* __restrict__ W,
    const unsigned long long* __restrict__ keys, float* __restrict__ emb_out,
    float* __restrict__ idsf, float* __restrict__ partials) {
    int wid = threadIdx.x >> 6;
    int lane = threadIdx.x & 63;
    int tok = blockIdx.x * 4 + wid;
    int id = (int)(unsigned)(keys[tok] & 0xffffffffull);
    if (lane == 0) idsf[tok] = (float)id;
    const float* wr = W + (size_t)id * DIM;
    const float* xr = x + (size_t)tok * DIM;
    float* orow = emb_out + (size_t)tok * DIM;
    float s = 0.f;
#pragma unroll
    for (int q = 0; q < 2; ++q) {
        int d = q * 256 + lane * 4;
        float4 wv = *(const float4*)(wr + d);
        float4 xv = *(const float4*)(xr + d);
        float4 e = {xv.x + (wv.x - xv.x), xv.y + (wv.y - xv.y),
                    xv.z + (wv.z - xv.z), xv.w + (wv.w - xv.w)};
        *(float4*)(orow + d) = e;
        float dx = xv.x - wv.x, dy = xv.y - wv.y, dz = xv.z - wv.z, dw = xv.w - wv.w;
        s += dx * dx + dy * dy + dz * dz + dw * dw;
    }
#pragma unroll
    for (int off = 32; off > 0; off >>= 1) s += __shfl_down(s, off);
    __shared__ float bsum[4];
    if (lane == 0) bsum[wid] = s;
    __syncthreads();
    if (threadIdx.x == 0)
        partials[blockIdx.x] = bsum[0] + bsum[1] + bsum[2] + bsum[3];
}

// ================= round-1 fp32 fallback (if ws too small) =================
#define BN 64
#define BK 64
#define DC 32
#define PAD 68
__global__ __launch_bounds__(256) void argmin_kernel(const float* __restrict__ x,
                                                     const float* __restrict__ W,
                                                     const float* __restrict__ c2,
                                                     float* __restrict__ idsf) {
    __shared__ float xs[DC][PAD];
    __shared__ float wt[DC][PAD];
    __shared__ float c2s[BK];
    __shared__ float redv[16][BN];
    __shared__ int redi[16][BN];
    const int tid = threadIdx.x;
    const int n0 = blockIdx.x * BN;
    const int i = tid & 15;
    const int j = tid >> 4;
    float bestv[4];
    int besti[4];
#pragma unroll
    for (int t = 0; t < 4; ++t) { bestv[t] = 3.4e38f; besti[t] = 0; }
    for (int k0 = 0; k0 < KC; k0 += BK) {
        __syncthreads();
        if (tid < BK) c2s[tid] = c2[k0 + tid];
        float acc[4][4];
#pragma unroll
        for (int a = 0; a < 4; ++a)
#pragma unroll
            for (int b = 0; b < 4; ++b) acc[a][b] = 0.f;
        for (int d0 = 0; d0 < DIM; d0 += DC) {
            __syncthreads();
#pragma unroll
            for (int r = 0; r < 2; ++r) {
                int f = tid + r * 256;
                int tok = f >> 3;
                int dq = f & 7;
                float4 xv = *(const float4*)(x + (size_t)(n0 + tok) * DIM + d0 + dq * 4);
                float4 wv = *(const float4*)(W + (size_t)(k0 + tok) * DIM + d0 + dq * 4);
                xs[dq * 4 + 0][tok] = xv.x; xs[dq * 4 + 1][tok] = xv.y;
                xs[dq * 4 + 2][tok] = xv.z; xs[dq * 4 + 3][tok] = xv.w;
                wt[dq * 4 + 0][tok] = wv.x; wt[dq * 4 + 1][tok] = wv.y;
                wt[dq * 4 + 2][tok] = wv.z; wt[dq * 4 + 3][tok] = wv.w;
            }
            __syncthreads();
#pragma unroll
            for (int d = 0; d < DC; ++d) {
                float4 xv = *(const float4*)(&xs[d][i * 4]);
                float4 wv = *(const float4*)(&wt[d][j * 4]);
#pragma unroll
                for (int a = 0; a < 4; ++a) {
                    float xa = (a == 0) ? xv.x : (a == 1) ? xv.y : (a == 2) ? xv.z : xv.w;
                    acc[a][0] = fmaf(xa, wv.x, acc[a][0]);
                    acc[a][1] = fmaf(xa, wv.y, acc[a][1]);
                    acc[a][2] = fmaf(xa, wv.z, acc[a][2]);
                    acc[a][3] = fmaf(xa, wv.w, acc[a][3]);
                }
            }
        }
#pragma unroll
        for (int ti = 0; ti < 4; ++ti)
#pragma unroll
            for (int cj = 0; cj < 4; ++cj) {
                float s = c2s[j * 4 + cj] - 2.f * acc[ti][cj];
                int kk = k0 + j * 4 + cj;
                if (s < bestv[ti]) { bestv[ti] = s; besti[ti] = kk; }
            }
    }
#pragma unroll
    for (int ti = 0; ti < 4; ++ti) {
        redv[j][i * 4 + ti] = bestv[ti];
        redi[j][i * 4 + ti] = besti[ti];
    }
    __syncthreads();
    if (tid < BN) {
        float bv = redv[0][tid];
        int bi = redi[0][tid];
#pragma unroll
        for (int jj = 1; jj < 16; ++jj) {
            float v = redv[jj][tid];
            int ii = redi[jj][tid];
            if (v < bv || (v == bv && ii < bi)) { bv = v; bi = ii; }
        }
        idsf[n0 + tid] = (float)bi;
    }
}

__global__ __launch_bounds__(256) void gather_kernel(const float* __restrict__ x,
                                                     const float* __restrict__ W,
                                                     const float* __restrict__ idsf,
                                                     float* __restrict__ emb_out,
                                                     float* __restrict__ partials) {
    int wid = threadIdx.x >> 6;
    int lane = threadIdx.x & 63;
    int tok = blockIdx.x * 4 + wid;
    int id = (int)idsf[tok];
    const float* wr = W + (size_t)id * DIM;
    const float* xr = x + (size_t)tok * DIM;
    float* orow = emb_out + (size_t)tok * DIM;
    float s = 0.f;
#pragma unroll
    for (int q = 0; q < 2; ++q) {
        int d = q * 256 + lane * 4;
        float4 wv = *(const float4*)(wr + d);
        float4 xv = *(const float4*)(xr + d);
        float4 e = {wv.x, wv.y, wv.z, wv.w};
        *(float4*)(orow + d) = e;
        float dx = xv.x - wv.x, dy = xv.y - wv.y, dz = xv.z - wv.z, dw = xv.w - wv.w;
        s += dx * dx + dy * dy + dz * dz + dw * dw;
    }
#pragma unroll
    for (int off = 32; off > 0; off >>= 1) s += __shfl_down(s, off);
    __shared__ float bsum[4];
    if (lane == 0) bsum[wid] = s;
    __syncthreads();
    if (threadIdx.x == 0)
        partials[blockIdx.x] = bsum[0] + bsum[1] + bsum[2] + bsum[3];
}

// ================= host =================
extern "C" void kernel_launch(void* const* d_in, const int* in_sizes, int n_in,
                              void* d_out, int out_size, void* d_ws, size_t ws_size,
                              hipStream_t stream) {
    const float* x = (const float*)d_in[0];
    const float* W = (const float*)d_in[2];

    float* out = (float*)d_out;
    float* emb_out = out;
    float* idsf = out + (size_t)NTOK * DIM;
    float* lossp = idsf + NTOK;

    const size_t W12_BYTES = (size_t)KC * DIM * 4;  // 16 MB fp16 hi+lo planes
    const size_t KEYS_BYTES = (size_t)NTOK * 8;
    size_t need = W12_BYTES + KEYS_BYTES + (size_t)KC * 4 + (size_t)(NTOK / 4) * 4;

    if (ws_size >= need) {
        u16* w12 = (u16*)d_ws;
        unsigned long long* keys = (unsigned long long*)((char*)d_ws + W12_BYTES);
        float* c2 = (float*)((char*)keys + KEYS_BYTES);
        float* partials = c2 + KC;
        u16* x12 = (u16*)emb_out;  // 64 MB emb region doubles as x-split scratch

        split_kernel<<<NTOK * 64 / 256, 256, 0, stream>>>(x, x12);
        split_kernel<<<KC * 64 / 256, 256, 0, stream>>>(W, w12);
        c2_kernel<<<KC / 4, 256, 0, stream>>>(W, c2);
        init_keys_kernel<<<NTOK / 256, 256, 0, stream>>>(keys);
        argmin_mfma_kernel<<<(NTOK / 128) * (KC / 128), 256, 0, stream>>>(x12, w12, c2, keys);
        gather_keys_kernel<<<NTOK / 4, 256, 0, stream>>>(x, W, keys, emb_out, idsf, partials);
        loss_kernel<<<1, 256, 0, stream>>>(partials, lossp);
    } else {
        float* c2 = (float*)d_ws;
        float* partials = c2 + KC;
        c2_kernel<<<KC / 4, 256, 0, stream>>>(W, c2);
        argmin_kernel<<<NTOK / BN, 256, 0, stream>>>(x, W, c2, idsf);
        gather_kernel<<<NTOK / 4, 256, 0, stream>>>(x, W, idsf, emb_out, partials);
        loss_kernel<<<1, 256, 0, stream>>>(partials, lossp);
    }
}

// Round 3
// 958.729 us; speedup vs baseline: 4.5650x; 1.5904x over previous
//
#include <hip/hip_runtime.h>
#include <math.h>

#define NTOK 32768
#define DIM 512
#define KC 8192

// ---- MFMA pipeline geometry ----
#define BM 256
#define BN 256
#define HSTEPS 16            // hi-plane K-steps per plane (512 / 32)
#define VSTEPS 48            // virtual steps: A1B1(16) + A2B1(16) + A1B2(16)
#define NBUF 4
#define STEP_U16 8192        // 256 rows x 32 halves = 16 KB per step per matrix

typedef unsigned short u16;
typedef _Float16 half8 __attribute__((ext_vector_type(8)));
typedef float f32x4 __attribute__((ext_vector_type(4)));

// ---- async global->LDS, 16B per lane (dest = wave-uniform base + lane*16) ----
__device__ __forceinline__ void gload16(const void* g, void* l) {
    __builtin_amdgcn_global_load_lds(
        (const __attribute__((address_space(1))) unsigned int*)(void*)g,
        (__attribute__((address_space(3))) unsigned int*)l, 16, 0, 0);
}

// ================= small kernels =================
__global__ __launch_bounds__(256) void c2_kernel(const float* __restrict__ W,
                                                 float* __restrict__ c2) {
    int wid = threadIdx.x >> 6;
    int lane = threadIdx.x & 63;
    int row = blockIdx.x * 4 + wid;
    const float* wr = W + (size_t)row * DIM;
    float s = 0.f;
#pragma unroll
    for (int q = 0; q < 2; ++q) {
        float4 v = *(const float4*)(wr + q * 256 + lane * 4);
        s += v.x * v.x + v.y * v.y + v.z * v.z + v.w * v.w;
    }
#pragma unroll
    for (int off = 32; off > 0; off >>= 1) s += __shfl_down(s, off);
    if (lane == 0) c2[row] = s;
}

__global__ __launch_bounds__(256) void loss_kernel(const float* __restrict__ partials,
                                                   float* __restrict__ lossp) {
    __shared__ float red[256];
    float s = 0.f;
    for (int idx = threadIdx.x; idx < NTOK / 4; idx += 256) s += partials[idx];
    red[threadIdx.x] = s;
    __syncthreads();
    for (int off = 128; off > 0; off >>= 1) {
        if (threadIdx.x < off) red[threadIdx.x] += red[threadIdx.x + off];
        __syncthreads();
    }
    if (threadIdx.x == 0) lossp[0] = 1.25f * red[0] / (float)NTOK;
}

__global__ void init_keys_kernel(unsigned long long* keys) {
    keys[blockIdx.x * 256 + threadIdx.x] = ~0ull;
}

// ================= split: fp32 -> fp16 hi/lo planes, pre-swizzled tile layout =================
// Per matrix: tiles of 256 rows; per tile 32 steps (0-15 hi, 16-31 lo);
// per step: 256 rows x 32 halves (64 B/row = 4 chunks of 16 B);
// chunk c of row Rl stored at slot c ^ ((Rl>>1)&3)  -> conflict-free ds_read_b128
// after LINEAR global_load_lds staging (swizzle lives on the global side).
__global__ __launch_bounds__(256) void split_kernel(const float* __restrict__ src,
                                                    u16* __restrict__ dst) {
    int lane = threadIdx.x & 63;
    int wid = threadIdx.x >> 6;
    int row = blockIdx.x * 64 + lane;
    int s = blockIdx.y * 4 + wid;          // hi step 0..15
    const float* p = src + (size_t)row * DIM + s * 32;
    int tile = row >> 8, Rl = row & 255, swz = (Rl >> 1) & 3;
    u16* baseH = dst + ((size_t)(tile * 32 + s) * 256 + Rl) * 32;
    u16* baseL = baseH + (size_t)HSTEPS * STEP_U16;
#pragma unroll
    for (int c = 0; c < 4; ++c) {
        float4 va = ((const float4*)p)[c * 2];
        float4 vb = ((const float4*)p)[c * 2 + 1];
        float f[8] = {va.x, va.y, va.z, va.w, vb.x, vb.y, vb.z, vb.w};
        unsigned H[4], L[4];
#pragma unroll
        for (int j = 0; j < 4; ++j) {
            _Float16 h0 = (_Float16)f[2 * j];
            _Float16 g0 = (_Float16)(f[2 * j] - (float)h0);
            _Float16 h1 = (_Float16)f[2 * j + 1];
            _Float16 g1 = (_Float16)(f[2 * j + 1] - (float)h1);
            H[j] = (unsigned)__builtin_bit_cast(u16, h0) |
                   ((unsigned)__builtin_bit_cast(u16, h1) << 16);
            L[j] = (unsigned)__builtin_bit_cast(u16, g0) |
                   ((unsigned)__builtin_bit_cast(u16, g1) << 16);
        }
        int slot = (c ^ swz) * 8;
        *(uint4*)(baseH + slot) = uint4{H[0], H[1], H[2], H[3]};
        *(uint4*)(baseL + slot) = uint4{L[0], L[1], L[2], L[3]};
    }
}

// ================= fused GEMM + argmin, depth-3 counted-vmcnt pipeline =================
__global__ __launch_bounds__(512, 2) void argmin_mfma_kernel(
    const u16* __restrict__ xscr, const u16* __restrict__ wscr,
    const float* __restrict__ c2, unsigned long long* __restrict__ keys) {
    __shared__ __align__(16) u16 Ab[NBUF][STEP_U16];   // 4 x 16 KB
    __shared__ __align__(16) u16 Bb[NBUF][STEP_U16];   // 4 x 16 KB  (total 128 KB)

    // XCD-aware swizzle (4096 % 8 == 0 -> bijective)
    int cpx = (int)gridDim.x >> 3;
    int bid = (int)blockIdx.x;
    int wg = (bid & 7) * cpx + (bid >> 3);
    int tcol = wg & 31;    // 32 code tiles of 256
    int trow = wg >> 5;    // 128 token tiles of 256

    const int tid = threadIdx.x;
    const int lane = tid & 63;
    const int w = tid >> 6;
    const int wr = w >> 2;           // M half (128 rows)
    const int wc = w & 3;            // N quarter (64 cols)

    const u16* gA = xscr + (size_t)trow * (32 * STEP_U16);
    const u16* gB = wscr + (size_t)tcol * (32 * STEP_U16);

    const int l15 = lane & 15, q = lane >> 4;
    float c2v[4];
    const int colbase = tcol * 256 + wc * 64 + l15;
#pragma unroll
    for (int n = 0; n < 4; ++n) c2v[n] = c2[colbase + n * 16];

    f32x4 acc[8][4];
#pragma unroll
    for (int m = 0; m < 8; ++m)
#pragma unroll
        for (int n = 0; n < 4; ++n) acc[m][n] = f32x4{0.f, 0.f, 0.f, 0.f};

    const int swz = (l15 >> 1) & 3;
    const int aoff0 = (wr * 128 + l15) * 32 + (q ^ swz) * 8;  // u16 index
    const int boff0 = (wc * 64 + l15) * 32 + (q ^ swz) * 8;
    const int wo = w * 512;          // wave's 1 KB slice (u16 units)
    const int lo8 = lane * 8;        // lane's 16 B (global side only)

    // prologue: stage virtual tiles 0,1,2 (sa=sb=v for v<16)
#pragma unroll
    for (int p = 0; p < 3; ++p) {
        const u16* ga = gA + (size_t)p * STEP_U16;
        const u16* gb = gB + (size_t)p * STEP_U16;
#pragma unroll
        for (int r = 0; r < 2; ++r) {
            gload16(ga + r * 4096 + wo + lo8, Ab[p] + r * 4096 + wo);
            gload16(gb + r * 4096 + wo + lo8, Bb[p] + r * 4096 + wo);
        }
    }
    asm volatile("s_waitcnt vmcnt(8)" ::: "memory");   // tile 0 landed
    __builtin_amdgcn_s_barrier();
    __builtin_amdgcn_sched_barrier(0);

#pragma unroll 4
    for (int v = 0; v < VSTEPS; ++v) {
        // issue prefetch of tile v+3 into the buffer freed at end of iter v-1
        if (v + 3 < VSTEPS) {
            int u = v + 3;
            int sa = (u < 32) ? u : u - 32;       // A: hi | lo | hi
            int sb = (u < 16) ? u : u - 16;       // B: hi | hi | lo
            const u16* ga = gA + (size_t)sa * STEP_U16;
            const u16* gb = gB + (size_t)sb * STEP_U16;
            u16* la = Ab[u & 3];
            u16* lb = Bb[u & 3];
#pragma unroll
            for (int r = 0; r < 2; ++r) {
                gload16(ga + r * 4096 + wo + lo8, la + r * 4096 + wo);
                gload16(gb + r * 4096 + wo + lo8, lb + r * 4096 + wo);
            }
        }
        const u16* A = Ab[v & 3];
        const u16* B = Bb[v & 3];
        half8 b[4], a[8];
#pragma unroll
        for (int n = 0; n < 4; ++n) b[n] = *(const half8*)(B + boff0 + n * 512);
#pragma unroll
        for (int m = 0; m < 8; ++m) a[m] = *(const half8*)(A + aoff0 + m * 512);
        __builtin_amdgcn_s_setprio(1);
#pragma unroll
        for (int m = 0; m < 8; ++m)
#pragma unroll
            for (int n = 0; n < 4; ++n)
                acc[m][n] = __builtin_amdgcn_mfma_f32_16x16x32_f16(a[m], b[n], acc[m][n], 0, 0, 0);
        __builtin_amdgcn_s_setprio(0);
        // counted wait: tiles v+2, v+3 may stay in flight (8 loads); v+1 landed
        asm volatile("s_waitcnt vmcnt(8)" ::: "memory");
        __builtin_amdgcn_s_barrier();
        __builtin_amdgcn_sched_barrier(0);
    }

    // ---- epilogue: scores + argmin; block-level key reduce in LDS ----
    unsigned long long* kbuf = (unsigned long long*)&Ab[0][0];  // [4][256], buffers dead
#pragma unroll
    for (int m = 0; m < 8; ++m) {
#pragma unroll
        for (int r = 0; r < 4; ++r) {
            float bv = 3.4e38f;
            int bi = 0;
#pragma unroll
            for (int n = 0; n < 4; ++n) {
                float sc = c2v[n] - 2.0f * acc[m][n][r];
                int idx = colbase + n * 16;
                if (sc < bv) { bv = sc; bi = idx; }
            }
#pragma unroll
            for (int off = 1; off < 16; off <<= 1) {
                float ov = __shfl_xor(bv, off);
                int oi = __shfl_xor(bi, off);
                if (ov < bv || (ov == bv && oi < bi)) { bv = ov; bi = oi; }
            }
            if (l15 == 0) {
                unsigned u = __float_as_uint(bv);
                u = (u & 0x80000000u) ? ~u : (u | 0x80000000u);
                kbuf[wc * 256 + wr * 128 + m * 16 + q * 4 + r] =
                    ((unsigned long long)u << 32) | (unsigned)bi;
            }
        }
    }
    __syncthreads();
    if (tid < 256) {
        unsigned long long k = kbuf[tid];
#pragma unroll
        for (int c = 1; c < 4; ++c) {
            unsigned long long o = kbuf[c * 256 + tid];
            if (o < k) k = o;
        }
        atomicMin(&keys[trow * 256 + tid], k);
    }
}

// ================= gather + partial loss =================
__global__ __launch_bounds__(256) void gather_keys_kernel(
    const float* __restrict__ x, const float* __restrict__ W,
    const unsigned long long* __restrict__ keys, float* __restrict__ emb_out,
    float* __restrict__ idsf, float* __restrict__ partials) {
    int wid = threadIdx.x >> 6;
    int lane = threadIdx.x & 63;
    int tok = blockIdx.x * 4 + wid;
    int id = (int)(unsigned)(keys[tok] & 0xffffffffull);
    if (lane == 0) idsf[tok] = (float)id;
    const float* wr = W + (size_t)id * DIM;
    const float* xr = x + (size_t)tok * DIM;
    float* orow = emb_out + (size_t)tok * DIM;
    float s = 0.f;
#pragma unroll
    for (int q = 0; q < 2; ++q) {
        int d = q * 256 + lane * 4;
        float4 wv = *(const float4*)(wr + d);
        float4 xv = *(const float4*)(xr + d);
        float4 e = {xv.x + (wv.x - xv.x), xv.y + (wv.y - xv.y),
                    xv.z + (wv.z - xv.z), xv.w + (wv.w - xv.w)};
        *(float4*)(orow + d) = e;
        float dx = xv.x - wv.x, dy = xv.y - wv.y, dz = xv.z - wv.z, dw = xv.w - wv.w;
        s += dx * dx + dy * dy + dz * dz + dw * dw;
    }
#pragma unroll
    for (int off = 32; off > 0; off >>= 1) s += __shfl_down(s, off);
    __shared__ float bsum[4];
    if (lane == 0) bsum[wid] = s;
    __syncthreads();
    if (threadIdx.x == 0)
        partials[blockIdx.x] = bsum[0] + bsum[1] + bsum[2] + bsum[3];
}

// ================= fp32 fallback (ws too small; not expected) =================
#define FBN 64
#define FBK 64
#define FDC 32
#define FPAD 68
__global__ __launch_bounds__(256) void argmin_kernel(const float* __restrict__ x,
                                                     const float* __restrict__ W,
                                                     const float* __restrict__ c2,
                                                     float* __restrict__ idsf) {
    __shared__ float xs[FDC][FPAD];
    __shared__ float wt[FDC][FPAD];
    __shared__ float c2s[FBK];
    __shared__ float redv[16][FBN];
    __shared__ int redi[16][FBN];
    const int tid = threadIdx.x;
    const int n0 = blockIdx.x * FBN;
    const int i = tid & 15;
    const int j = tid >> 4;
    float bestv[4];
    int besti[4];
#pragma unroll
    for (int t = 0; t < 4; ++t) { bestv[t] = 3.4e38f; besti[t] = 0; }
    for (int k0 = 0; k0 < KC; k0 += FBK) {
        __syncthreads();
        if (tid < FBK) c2s[tid] = c2[k0 + tid];
        float acc[4][4];
#pragma unroll
        for (int a = 0; a < 4; ++a)
#pragma unroll
            for (int b = 0; b < 4; ++b) acc[a][b] = 0.f;
        for (int d0 = 0; d0 < DIM; d0 += FDC) {
            __syncthreads();
#pragma unroll
            for (int r = 0; r < 2; ++r) {
                int f = tid + r * 256;
                int tok = f >> 3;
                int dq = f & 7;
                float4 xv = *(const float4*)(x + (size_t)(n0 + tok) * DIM + d0 + dq * 4);
                float4 wv = *(const float4*)(W + (size_t)(k0 + tok) * DIM + d0 + dq * 4);
                xs[dq * 4 + 0][tok] = xv.x; xs[dq * 4 + 1][tok] = xv.y;
                xs[dq * 4 + 2][tok] = xv.z; xs[dq * 4 + 3][tok] = xv.w;
                wt[dq * 4 + 0][tok] = wv.x; wt[dq * 4 + 1][tok] = wv.y;
                wt[dq * 4 + 2][tok] = wv.z; wt[dq * 4 + 3][tok] = wv.w;
            }
            __syncthreads();
#pragma unroll
            for (int d = 0; d < FDC; ++d) {
                float4 xv = *(const float4*)(&xs[d][i * 4]);
                float4 wv = *(const float4*)(&wt[d][j * 4]);
#pragma unroll
                for (int a = 0; a < 4; ++a) {
                    float xa = (a == 0) ? xv.x : (a == 1) ? xv.y : (a == 2) ? xv.z : xv.w;
                    acc[a][0] = fmaf(xa, wv.x, acc[a][0]);
                    acc[a][1] = fmaf(xa, wv.y, acc[a][1]);
                    acc[a][2] = fmaf(xa, wv.z, acc[a][2]);
                    acc[a][3] = fmaf(xa, wv.w, acc[a][3]);
                }
            }
        }
#pragma unroll
        for (int ti = 0; ti < 4; ++ti)
#pragma unroll
            for (int cj = 0; cj < 4; ++cj) {
                float s = c2s[j * 4 + cj] - 2.f * acc[ti][cj];
                int kk = k0 + j * 4 + cj;
                if (s < bestv[ti]) { bestv[ti] = s; besti[ti] = kk; }
            }
    }
#pragma unroll
    for (int ti = 0; ti < 4; ++ti) {
        redv[j][i * 4 + ti] = bestv[ti];
        redi[j][i * 4 + ti] = besti[ti];
    }
    __syncthreads();
    if (tid < FBN) {
        float bv = redv[0][tid];
        int bi = redi[0][tid];
#pragma unroll
        for (int jj = 1; jj < 16; ++jj) {
            float v = redv[jj][tid];
            int ii = redi[jj][tid];
            if (v < bv || (v == bv && ii < bi)) { bv = v; bi = ii; }
        }
        idsf[n0 + tid] = (float)bi;
    }
}

__global__ __launch_bounds__(256) void gather_kernel(const float* __restrict__ x,
                                                     const float* __restrict__ W,
                                                     const float* __restrict__ idsf,
                                                     float* __restrict__ emb_out,
                                                     float* __restrict__ partials) {
    int wid = threadIdx.x >> 6;
    int lane = threadIdx.x & 63;
    int tok = blockIdx.x * 4 + wid;
    int id = (int)idsf[tok];
    const float* wr = W + (size_t)id * DIM;
    const float* xr = x + (size_t)tok * DIM;
    float* orow = emb_out + (size_t)tok * DIM;
    float s = 0.f;
#pragma unroll
    for (int q = 0; q < 2; ++q) {
        int d = q * 256 + lane * 4;
        float4 wv = *(const float4*)(wr + d);
        float4 xv = *(const float4*)(xr + d);
        float4 e = {xv.x + (wv.x - xv.x), xv.y + (wv.y - xv.y),
                    xv.z + (wv.z - xv.z), xv.w + (wv.w - xv.w)};
        *(float4*)(orow + d) = e;
        float dx = xv.x - wv.x, dy = xv.y - wv.y, dz = xv.z - wv.z, dw = xv.w - wv.w;
        s += dx * dx + dy * dy + dz * dz + dw * dw;
    }
#pragma unroll
    for (int off = 32; off > 0; off >>= 1) s += __shfl_down(s, off);
    __shared__ float bsum[4];
    if (lane == 0) bsum[wid] = s;
    __syncthreads();
    if (threadIdx.x == 0)
        partials[blockIdx.x] = bsum[0] + bsum[1] + bsum[2] + bsum[3];
}

// ================= host =================
extern "C" void kernel_launch(void* const* d_in, const int* in_sizes, int n_in,
                              void* d_out, int out_size, void* d_ws, size_t ws_size,
                              hipStream_t stream) {
    const float* x = (const float*)d_in[0];
    const float* W = (const float*)d_in[2];

    float* out = (float*)d_out;
    float* emb_out = out;
    float* idsf = out + (size_t)NTOK * DIM;
    float* lossp = idsf + NTOK;

    const size_t W12_BYTES = (size_t)KC * DIM * 4;  // 16 MB fp16 hi+lo planes
    const size_t KEYS_BYTES = (size_t)NTOK * 8;
    size_t need = W12_BYTES + KEYS_BYTES + (size_t)KC * 4 + (size_t)(NTOK / 4) * 4;

    if (ws_size >= need) {
        u16* w12 = (u16*)d_ws;
        unsigned long long* keys = (unsigned long long*)((char*)d_ws + W12_BYTES);
        float* c2 = (float*)((char*)keys + KEYS_BYTES);
        float* partials = c2 + KC;
        u16* x12 = (u16*)emb_out;  // 64 MB emb region doubles as x-split scratch

        split_kernel<<<dim3(NTOK / 64, 4), 256, 0, stream>>>(x, x12);
        split_kernel<<<dim3(KC / 64, 4), 256, 0, stream>>>(W, w12);
        c2_kernel<<<KC / 4, 256, 0, stream>>>(W, c2);
        init_keys_kernel<<<NTOK / 256, 256, 0, stream>>>(keys);
        argmin_mfma_kernel<<<(NTOK / BM) * (KC / BN), 512, 0, stream>>>(x12, w12, c2, keys);
        gather_keys_kernel<<<NTOK / 4, 256, 0, stream>>>(x, W, keys, emb_out, idsf, partials);
        loss_kernel<<<1, 256, 0, stream>>>(partials, lossp);
    } else {
        float* c2 = (float*)d_ws;
        float* partials = c2 + KC;
        c2_kernel<<<KC / 4, 256, 0, stream>>>(W, c2);
        argmin_kernel<<<NTOK / FBN, 256, 0, stream>>>(x, W, c2, idsf);
        gather_kernel<<<NTOK / 4, 256, 0, stream>>>(x, W, idsf, emb_out, partials);
        loss_kernel<<<1, 256, 0, stream>>>(partials, lossp);
    }
}